// Round 6
// baseline (403.207 us; speedup 1.0000x reference)
//
#include <hip/hip_runtime.h>
#include <hip/hip_bf16.h>
#include <math.h>

// Problem constants
#define LQ    512
#define DS    384
#define DPAIR 128
#define NH    12
#define NPP   1792   // padded projection width
#define FE    48     // logits feature dim (32 q + 12 pts + 2)
#define TJC   64     // j-chunk for pair kernel
#define NC    8      // number of j-chunks (LQ/TJC)

__device__ __forceinline__ unsigned int pk_bf2(float a, float b) {
  __hip_bfloat162 h = __float22bfloat162_rn(make_float2(a, b));
  union { __hip_bfloat162 h2; unsigned int u; } cv; cv.h2 = h; return cv.u;
}
__device__ __forceinline__ float blo(unsigned int u) { return __uint_as_float(u << 16); }
__device__ __forceinline__ float bhi(unsigned int u) { return __uint_as_float(u & 0xffff0000u); }

// ---------------------------------------------------------------- concat W (+ WpbT transpose)
__global__ void k_concat_w(const float* __restrict__ Wq, const float* __restrict__ Wk,
                           const float* __restrict__ Wv, const float* __restrict__ Wqp,
                           const float* __restrict__ Wkp, const float* __restrict__ Wvp,
                           const float* __restrict__ bq, const float* __restrict__ bk,
                           const float* __restrict__ bv, const float* __restrict__ bqp,
                           const float* __restrict__ bkp, const float* __restrict__ bvp,
                           const float* __restrict__ Wpb,
                           float* __restrict__ Wcat, float* __restrict__ bcat,
                           float* __restrict__ WpbT) {
  int idx = blockIdx.x * 256 + threadIdx.x;
  const int total = DS * NPP;
  if (idx < total) {
    int k = idx / NPP, c = idx % NPP;
    float v = 0.f;
    if (c < 384)       v = Wq[k*384 + c];
    else if (c < 768)  v = Wk[k*384 + c-384];
    else if (c < 1152) v = Wv[k*384 + c-768];
    else if (c < 1296) v = Wqp[k*144 + c-1152];
    else if (c < 1440) v = Wkp[k*144 + c-1296];
    else if (c < 1728) v = Wvp[k*288 + c-1440];
    Wcat[idx] = v;
  } else if (idx < total + NPP) {
    int c = idx - total;
    float v = 0.f;
    if (c < 384)       v = bq[c];
    else if (c < 768)  v = bk[c-384];
    else if (c < 1152) v = bv[c-768];
    else if (c < 1296) v = bqp[c-1152];
    else if (c < 1440) v = bkp[c-1296];
    else if (c < 1728) v = bvp[c-1440];
    bcat[c] = v;
  } else if (idx < total + NPP + DPAIR*NH) {
    int e = idx - total - NPP;
    int k = e / NH, h = e % NH;
    WpbT[h*DPAIR + k] = Wpb[e];
  }
}

// ---------------------------------------------------------------- layernorm
__global__ __launch_bounds__(128) void k_layernorm(const float* __restrict__ x,
                                                   const float* __restrict__ w,
                                                   const float* __restrict__ b,
                                                   float* __restrict__ y) {
  __shared__ float red[128];
  __shared__ float s_mu, s_rstd;
  int i = blockIdx.x, t = threadIdx.x;
  float v0 = x[i*DS + t], v1 = x[i*DS + t + 128], v2 = x[i*DS + t + 256];
  red[t] = v0 + v1 + v2; __syncthreads();
  for (int s = 64; s > 0; s >>= 1) { if (t < s) red[t] += red[t+s]; __syncthreads(); }
  if (t == 0) s_mu = red[0] * (1.f/384.f);
  __syncthreads();
  float mu = s_mu;
  float d0 = v0-mu, d1 = v1-mu, d2 = v2-mu;
  red[t] = d0*d0 + d1*d1 + d2*d2; __syncthreads();
  for (int s = 64; s > 0; s >>= 1) { if (t < s) red[t] += red[t+s]; __syncthreads(); }
  if (t == 0) s_rstd = rsqrtf(red[0] * (1.f/384.f) + 1e-5f);
  __syncthreads();
  float r = s_rstd;
  y[i*DS + t      ] = d0*r*w[t      ] + b[t      ];
  y[i*DS + t + 128] = d1*r*w[t + 128] + b[t + 128];
  y[i*DS + t + 256] = d2*r*w[t + 256] + b[t + 256];
}

// ---------------------------------------------------------------- tiled f32 GEMM (NN), optional split-K
__global__ __launch_bounds__(256) void k_gemm_nn(const float* __restrict__ A,
                                                 const float* __restrict__ B,
                                                 const float* __restrict__ bias,
                                                 float* __restrict__ C,
                                                 float* __restrict__ Cpart,
                                                 int M, int N, int K) {
  __shared__ float As[16*68];
  __shared__ float Bs[16*68];
  int t = threadIdx.x;
  int mg = t >> 4, ng = t & 15;
  int i0 = blockIdx.y * 64, j0 = blockIdx.x * 64;
  int KS = gridDim.z;
  int kper = K / KS;
  int kbeg = blockIdx.z * kper;
  float acc[4][4] = {};
  for (int k0 = kbeg; k0 < kbeg + kper; k0 += 16) {
    int e = t;
    #pragma unroll
    for (int s = 0; s < 4; s++, e += 256) {
      int m = e >> 4, k = e & 15;
      As[k*68 + m] = A[(size_t)(i0+m)*K + k0 + k];
      int k2 = e >> 6, n = e & 63;
      Bs[k2*68 + n] = B[(size_t)(k0+k2)*N + j0 + n];
    }
    __syncthreads();
    #pragma unroll
    for (int k = 0; k < 16; k++) {
      float4 av = *(const float4*)(As + k*68 + mg*4);
      float4 bv = *(const float4*)(Bs + k*68 + ng*4);
      float a[4] = {av.x, av.y, av.z, av.w};
      float b[4] = {bv.x, bv.y, bv.z, bv.w};
      #pragma unroll
      for (int y = 0; y < 4; y++)
        #pragma unroll
        for (int x = 0; x < 4; x++)
          acc[y][x] = fmaf(a[y], b[x], acc[y][x]);
    }
    __syncthreads();
  }
  if (KS == 1) {
    #pragma unroll
    for (int y = 0; y < 4; y++) {
      int m = i0 + mg*4 + y;
      #pragma unroll
      for (int x = 0; x < 4; x++) {
        int n = j0 + ng*4 + x;
        C[(size_t)m*N + n] = acc[y][x] + bias[n];
      }
    }
  } else {
    float* dst = Cpart + (size_t)blockIdx.z * M * N;
    #pragma unroll
    for (int y = 0; y < 4; y++) {
      int m = i0 + mg*4 + y;
      #pragma unroll
      for (int x = 0; x < 4; x++) {
        int n = j0 + ng*4 + x;
        dst[(size_t)m*N + n] = acc[y][x];
      }
    }
  }
}

__global__ void k_reduce_bias(const float* __restrict__ part, const float* __restrict__ bias,
                              float* __restrict__ out, int MN, int N, int KS) {
  int e = blockIdx.x * 256 + threadIdx.x;
  if (e >= MN) return;
  float s = bias[e % N];
  for (int z = 0; z < KS; z++) s += part[(size_t)z*MN + e];
  out[e] = s;
}

// ---------------------------------------------------------------- fused rotate + feature build
// one thread per (i,h). Writes Af [h][i][48], BfT [h][kk][j] (float4 blocks), vgb.
__global__ void k_rotfeat(const float* __restrict__ C1, const float* __restrict__ rot,
                          const float* __restrict__ trans, const float* __restrict__ gamma,
                          const float* __restrict__ w_c, const float* __restrict__ w_l,
                          float* __restrict__ Af, float* __restrict__ BfT,
                          float* __restrict__ vgb) {
  int idx = blockIdx.x * 256 + threadIdx.x;
  if (idx >= LQ*NH) return;
  int h = idx % NH, i = idx / NH;
  float R[9], tr[3];
  #pragma unroll
  for (int r = 0; r < 9; r++) R[r] = rot[(size_t)i*9 + r];
  #pragma unroll
  for (int r = 0; r < 3; r++) tr[r] = trans[(size_t)i*3 + r];

  float s  = w_c[0] * rsqrtf(32.f);
  float gp = gamma[h] * w_l[0];
  float* a  = Af + ((size_t)h*LQ + i)*FE;
  float bb[48];
  const float* q = C1 + (size_t)i*NPP + h*32;
  const float* k = C1 + (size_t)i*NPP + 384 + h*32;
  #pragma unroll 8
  for (int d = 0; d < 32; d++) { a[d] = s*q[d]; bb[d] = k[d]; }

  const float* qp = C1 + (size_t)i*NPP + 1152 + h*12;
  const float* kp = C1 + (size_t)i*NPP + 1296 + h*12;
  float sq = 0.f, sk = 0.f;
  #pragma unroll
  for (int p = 0; p < 4; p++) {
    float x = qp[p*3], y = qp[p*3+1], z = qp[p*3+2];
    #pragma unroll
    for (int r = 0; r < 3; r++) {
      float g = fmaf(R[r*3],x, fmaf(R[r*3+1],y, fmaf(R[r*3+2],z, tr[r])));
      a[32 + p*3 + r] = gp*g;
      sq = fmaf(g,g,sq);
    }
    float xk = kp[p*3], yk = kp[p*3+1], zk = kp[p*3+2];
    #pragma unroll
    for (int r = 0; r < 3; r++) {
      float g = fmaf(R[r*3],xk, fmaf(R[r*3+1],yk, fmaf(R[r*3+2],zk, tr[r])));
      bb[32 + p*3 + r] = g;
      sk = fmaf(g,g,sk);
    }
  }
  a[44] = -0.5f*gp*sq; a[45] = 1.f; a[46] = 0.f; a[47] = 0.f;
  bb[44] = 1.f; bb[45] = -0.5f*gp*sk; bb[46] = 0.f; bb[47] = 0.f;

  #pragma unroll
  for (int kk = 0; kk < 12; kk++)
    *(float4*)&BfT[(((size_t)h*12 + kk)*LQ + i)*4] =
        make_float4(bb[4*kk], bb[4*kk+1], bb[4*kk+2], bb[4*kk+3]);

  const float* vp = C1 + (size_t)i*NPP + 1440 + h*24;
  float* vd = vgb + ((size_t)i*NH + h)*24;
  #pragma unroll
  for (int p = 0; p < 8; p++) {
    float x = vp[p*3], y = vp[p*3+1], z = vp[p*3+2];
    #pragma unroll
    for (int r = 0; r < 3; r++)
      vd[p*3 + r] = fmaf(R[r*3],x, fmaf(R[r*3+1],y, fmaf(R[r*3+2],z, tr[r])));
  }
}

// ---------------------------------------------------------------- pair chunk: logits + bias + chunk softmax + partial pair_out
// grid (i=512, c=8), 256 threads. bf16 LDS tile, xor-swizzled 16B chunks:
// logical chunk kc of row r lives at dword r*64 + ((kc^(r&15))<<2).
__global__ __launch_bounds__(256, 4) void k_pair_chunk(
    const float* __restrict__ pair, const float* __restrict__ WpbT,
    const float* __restrict__ Af, const float4* __restrict__ BfT4,
    const float* __restrict__ bpb, const float* __restrict__ mask,
    float* __restrict__ S, float* __restrict__ pairpart, float* __restrict__ msum) {
  __shared__ __align__(16) unsigned int tile[TJC*64];   // 16 KB bf16 tile
  __shared__ float wt[NH*TJC];                          // 3 KB
  int i = blockIdx.x, c = blockIdx.y, t = threadIdx.x;
  int j0 = c*TJC;

  // ---- stage pair tile f32 -> bf16 (coalesced 32B per thread per iter)
  {
    const float* src = pair + ((size_t)i*LQ + j0)*DPAIR;
    #pragma unroll
    for (int u = 0; u < 4; u++) {
      int e = t + u*256;
      int row = e >> 4, oct = e & 15;
      const float4* s4 = (const float4*)(src + (size_t)row*DPAIR + oct*8);
      float4 f0 = s4[0], f1 = s4[1];
      uint4 dv;
      dv.x = pk_bf2(f0.x, f0.y); dv.y = pk_bf2(f0.z, f0.w);
      dv.z = pk_bf2(f1.x, f1.y); dv.w = pk_bf2(f1.z, f1.w);
      *(uint4*)&tile[row*64 + ((oct ^ (row & 15)) << 2)] = dv;
    }
  }

  // ---- logits inline: l = bpb + Af[h][i] . Bf[h][j]   (3 heads per wave)
  int j = t & 63;
  int h0 = __builtin_amdgcn_readfirstlane(t >> 6) * 3;
  float l[3] = { bpb[h0], bpb[h0+1], bpb[h0+2] };
  {
    const float4* a0 = (const float4*)(Af + ((size_t)(h0+0)*LQ + i)*FE);
    const float4* a1 = (const float4*)(Af + ((size_t)(h0+1)*LQ + i)*FE);
    const float4* a2 = (const float4*)(Af + ((size_t)(h0+2)*LQ + i)*FE);
    const float4* b0 = BfT4 + ((size_t)(h0+0)*12)*LQ + j0 + j;
    const float4* b1 = BfT4 + ((size_t)(h0+1)*12)*LQ + j0 + j;
    const float4* b2 = BfT4 + ((size_t)(h0+2)*12)*LQ + j0 + j;
    #pragma unroll 4
    for (int kk = 0; kk < 12; kk++) {
      float4 av, bv;
      av = a0[kk]; bv = b0[(size_t)kk*LQ];
      l[0] = fmaf(av.x,bv.x, fmaf(av.y,bv.y, fmaf(av.z,bv.z, fmaf(av.w,bv.w, l[0]))));
      av = a1[kk]; bv = b1[(size_t)kk*LQ];
      l[1] = fmaf(av.x,bv.x, fmaf(av.y,bv.y, fmaf(av.z,bv.z, fmaf(av.w,bv.w, l[1]))));
      av = a2[kk]; bv = b2[(size_t)kk*LQ];
      l[2] = fmaf(av.x,bv.x, fmaf(av.y,bv.y, fmaf(av.z,bv.z, fmaf(av.w,bv.w, l[2]))));
    }
  }
  bool dead = (mask[i] * mask[j0 + j] <= 0.f);
  __syncthreads();   // tile staged

  // ---- phase A: pair-bias GEMV from bf16 tile, weights wave-uniform
  {
    const float* w0p = WpbT + (size_t)(h0+0)*DPAIR;
    const float* w1p = WpbT + (size_t)(h0+1)*DPAIR;
    const float* w2p = WpbT + (size_t)(h0+2)*DPAIR;
    int jx = j & 15;
    #pragma unroll 4
    for (int kk = 0; kk < 16; kk++) {
      uint4 d = *(const uint4*)&tile[j*64 + ((kk ^ jx) << 2)];
      float p0 = blo(d.x), p1 = bhi(d.x), p2 = blo(d.y), p3 = bhi(d.y);
      float p4 = blo(d.z), p5 = bhi(d.z), p6 = blo(d.w), p7 = bhi(d.w);
      int kb = kk*8;
      float4 wa, wb;
      wa = *(const float4*)(w0p + kb); wb = *(const float4*)(w0p + kb + 4);
      l[0] = fmaf(p0,wa.x, fmaf(p1,wa.y, fmaf(p2,wa.z, fmaf(p3,wa.w,
             fmaf(p4,wb.x, fmaf(p5,wb.y, fmaf(p6,wb.z, fmaf(p7,wb.w, l[0]))))))));
      wa = *(const float4*)(w1p + kb); wb = *(const float4*)(w1p + kb + 4);
      l[1] = fmaf(p0,wa.x, fmaf(p1,wa.y, fmaf(p2,wa.z, fmaf(p3,wa.w,
             fmaf(p4,wb.x, fmaf(p5,wb.y, fmaf(p6,wb.z, fmaf(p7,wb.w, l[1]))))))));
      wa = *(const float4*)(w2p + kb); wb = *(const float4*)(w2p + kb + 4);
      l[2] = fmaf(p0,wa.x, fmaf(p1,wa.y, fmaf(p2,wa.z, fmaf(p3,wa.w,
             fmaf(p4,wb.x, fmaf(p5,wb.y, fmaf(p6,wb.z, fmaf(p7,wb.w, l[2]))))))));
    }
  }
  if (dead) { l[0] = -1e9f; l[1] = -1e9f; l[2] = -1e9f; }

  // ---- chunk softmax: per-wave shuffle reduce, 3 heads
  #pragma unroll
  for (int q = 0; q < 3; q++) {
    float m = l[q];
    #pragma unroll
    for (int o = 32; o > 0; o >>= 1) m = fmaxf(m, __shfl_xor(m, o, 64));
    float w = __expf(l[q] - m);
    float sm = w;
    #pragma unroll
    for (int o = 32; o > 0; o >>= 1) sm += __shfl_xor(sm, o, 64);
    wt[(h0+q)*TJC + j] = w;
    S[((size_t)(h0+q)*LQ + i)*LQ + j0 + j] = w;
    if (j == 0) {
      float* dst = msum + (((size_t)i*NC + c)*NH + h0 + q)*2;
      dst[0] = m; dst[1] = sm;
    }
  }
  __syncthreads();

  // ---- phase C: partial pair_out from bf16 tile
  int dg = t & 31, strip = t >> 5, jb = strip*8;
  float4 pv[8];
  #pragma unroll
  for (int q = 0; q < 8; q++) {
    int row = jb + q;
    uint2 d = *(const uint2*)&tile[row*64 + (((dg >> 1) ^ (row & 15)) << 2) + (dg & 1)*2];
    pv[q] = make_float4(blo(d.x), bhi(d.x), blo(d.y), bhi(d.y));
  }
  float4 acc[NH];
  #pragma unroll
  for (int h = 0; h < NH; h++) acc[h] = make_float4(0.f,0.f,0.f,0.f);
  #pragma unroll
  for (int h = 0; h < NH; h++) {
    float4 w0 = *(const float4*)&wt[h*TJC + jb];
    float4 w1 = *(const float4*)&wt[h*TJC + jb + 4];
    float wq[8] = {w0.x,w0.y,w0.z,w0.w,w1.x,w1.y,w1.z,w1.w};
    float4 a = acc[h];
    #pragma unroll
    for (int q = 0; q < 8; q++) {
      a.x = fmaf(wq[q], pv[q].x, a.x);
      a.y = fmaf(wq[q], pv[q].y, a.y);
      a.z = fmaf(wq[q], pv[q].z, a.z);
      a.w = fmaf(wq[q], pv[q].w, a.w);
    }
    acc[h] = a;
  }
  __syncthreads();   // tile dead; reuse as reduction scratch

  // ---- reduce 8 strips in 4 rounds of 2 -> pairpart
  float4* red4 = (float4*)tile;   // 2*12*32 = 768 float4 = 12 KB <= 16 KB
  float4 tot[2];
  tot[0] = make_float4(0.f,0.f,0.f,0.f);
  tot[1] = make_float4(0.f,0.f,0.f,0.f);
  #pragma unroll
  for (int qtr = 0; qtr < 4; qtr++) {
    if ((strip >> 1) == qtr) {
      #pragma unroll
      for (int h = 0; h < NH; h++)
        red4[((strip & 1)*NH + h)*32 + dg] = acc[h];
    }
    __syncthreads();
    for (int e = t, u = 0; e < NH*32; e += 256, u++) {
      int rh = e >> 5, rd = e & 31;
      float4 v0 = red4[(rh)*32 + rd];
      float4 v1 = red4[(NH + rh)*32 + rd];
      tot[u].x += v0.x + v1.x; tot[u].y += v0.y + v1.y;
      tot[u].z += v0.z + v1.z; tot[u].w += v0.w + v1.w;
    }
    __syncthreads();
  }
  for (int e = t, u = 0; e < NH*32; e += 256, u++) {
    int rh = e >> 5, rd = e & 31;
    *(float4*)&pairpart[(((size_t)i*NC + c)*NH + rh)*DPAIR + rd*4] = tot[u];
  }
}

// ---------------------------------------------------------------- per-chunk softmax scales + pair_out combine
__global__ __launch_bounds__(384) void k_scs_pairout(
    const float* __restrict__ msum, const float* __restrict__ pairpart,
    float* __restrict__ scs_g, float* __restrict__ comb) {
  __shared__ float scs[NH*NC];
  int i = blockIdx.x, t = threadIdx.x;
  if (t < NH) {
    float m = -3.0e38f;
    float mc[NC], sc_[NC];
    #pragma unroll
    for (int c = 0; c < NC; c++) {
      const float* p = msum + (((size_t)i*NC + c)*NH + t)*2;
      mc[c] = p[0]; sc_[c] = p[1];
      m = fmaxf(m, mc[c]);
    }
    float s = 0.f;
    #pragma unroll
    for (int c = 0; c < NC; c++) s += sc_[c] * __expf(mc[c] - m);
    float inv = 1.f / s;
    #pragma unroll
    for (int c = 0; c < NC; c++) {
      float v = __expf(mc[c] - m) * inv;
      scs[t*NC + c] = v;
      scs_g[((size_t)i*NH + t)*NC + c] = v;
    }
  }
  __syncthreads();
  int h = t >> 5, d = t & 31;
  float4 tot = make_float4(0.f,0.f,0.f,0.f);
  #pragma unroll
  for (int c = 0; c < NC; c++) {
    float sc = scs[h*NC + c];
    float4 v = *(const float4*)&pairpart[(((size_t)i*NC + c)*NH + h)*DPAIR + d*4];
    tot.x = fmaf(v.x, sc, tot.x); tot.y = fmaf(v.y, sc, tot.y);
    tot.z = fmaf(v.z, sc, tot.z); tot.w = fmaf(v.w, sc, tot.w);
  }
  *(float4*)&comb[(size_t)i*2304 + 768 + h*DPAIR + d*4] = tot;
}

// ---------------------------------------------------------------- attn @ [v | vg] per head, split-K=4 -> psum
__global__ __launch_bounds__(256) void k_attn_v(const float* __restrict__ attn,
                                                const float* __restrict__ C1,
                                                const float* __restrict__ vg,
                                                const float* __restrict__ scs,
                                                float* __restrict__ psum) {
  __shared__ float As[64*68];   // [j][m] (transposed)
  __shared__ float Vs[64*68];   // [j][n], n<56 valid
  int i0 = blockIdx.x * 64;
  int h = blockIdx.y;
  int z = blockIdx.z;
  int t = threadIdx.x;
  int mg = t >> 4, ng = t & 15;
  float acc[4][4] = {};
  for (int k0 = z*128; k0 < z*128 + 128; k0 += 64) {
    int c = k0 >> 6;
    __syncthreads();
    for (int e = t; e < 64*64; e += 256) {
      int m = e >> 6, j = e & 63;
      float sc = scs[((size_t)(i0+m)*NH + h)*NC + c];
      As[j*68 + m] = attn[((size_t)h*LQ + i0 + m)*LQ + k0 + j] * sc;
    }
    for (int e = t; e < 64*64; e += 256) {
      int j = e >> 6, cc = e & 63;
      float v = 0.f;
      if (cc < 32)      v = C1[(size_t)(k0+j)*NPP + 768 + h*32 + cc];
      else if (cc < 56) v = vg[((size_t)(k0+j)*NH + h)*24 + (cc-32)];
      Vs[j*68 + cc] = v;
    }
    __syncthreads();
    #pragma unroll 4
    for (int j = 0; j < 64; j++) {
      float4 av = *(const float4*)(As + j*68 + mg*4);
      float4 bv = *(const float4*)(Vs + j*68 + ng*4);
      float a[4] = {av.x, av.y, av.z, av.w};
      float b[4] = {bv.x, bv.y, bv.z, bv.w};
      #pragma unroll
      for (int y = 0; y < 4; y++)
        #pragma unroll
        for (int x = 0; x < 4; x++)
          acc[y][x] = fmaf(a[y], b[x], acc[y][x]);
    }
  }
  #pragma unroll
  for (int y = 0; y < 4; y++) {
    int i = i0 + mg*4 + y;
    #pragma unroll
    for (int x = 0; x < 4; x++) {
      int n = ng*4 + x;
      psum[(((size_t)z*LQ + i)*NH + h)*64 + n] = acc[y][x];
    }
  }
}

// ---------------------------------------------------------------- fused av_reduce + pts_feat
__global__ void k_avpts(const float* __restrict__ psum, const float* __restrict__ rot,
                        const float* __restrict__ trans, float* __restrict__ comb) {
  int idx = blockIdx.x * 256 + threadIdx.x;
  if (idx >= LQ*NH*40) return;
  int w = idx % 40; int ih = idx / 40; int h = ih % NH; int i = ih / NH;
  size_t base = ((size_t)i*NH + h)*64;
  if (w < 32) {
    float s = 0.f;
    for (int z = 0; z < 4; z++) s += psum[(size_t)z*LQ*NH*64 + base + w];
    comb[(size_t)i*2304 + h*32 + w] = s;
  } else {
    int p = w - 32;
    float g[3];
    #pragma unroll
    for (int r = 0; r < 3; r++) {
      int n = 32 + p*3 + r;
      float s = 0.f;
      for (int z = 0; z < 4; z++) s += psum[(size_t)z*LQ*NH*64 + base + n];
      g[r] = s;
    }
    const float* R = rot + (size_t)i*9;
    const float* tr = trans + (size_t)i*3;
    float x = g[0]-tr[0], y = g[1]-tr[1], z = g[2]-tr[2];
    float lx = fmaf(R[0],x, fmaf(R[3],y, R[6]*z));
    float ly = fmaf(R[1],x, fmaf(R[4],y, R[7]*z));
    float lz = fmaf(R[2],x, fmaf(R[5],y, R[8]*z));
    float nrm = sqrtf(fmaf(lx,lx, fmaf(ly,ly, lz*lz)));
    float* dst = comb + (size_t)i*2304 + 384 + (h*8 + p)*4;
    dst[0] = nrm; dst[1] = lx; dst[2] = ly; dst[3] = lz;
  }
}

// ================================================================ launcher
extern "C" void kernel_launch(void* const* d_in, const int* in_sizes, int n_in,
                              void* d_out, int out_size, void* d_ws, size_t ws_size,
                              hipStream_t stream) {
  const float* single = (const float*)d_in[0];
  const float* pair   = (const float*)d_in[1];
  const float* rot    = (const float*)d_in[2];
  const float* trans  = (const float*)d_in[3];
  const float* mask   = (const float*)d_in[4];
  const float* ln_w   = (const float*)d_in[5];
  const float* ln_b   = (const float*)d_in[6];
  const float* Wq     = (const float*)d_in[7];
  const float* bq     = (const float*)d_in[8];
  const float* Wk     = (const float*)d_in[9];
  const float* bk     = (const float*)d_in[10];
  const float* Wv     = (const float*)d_in[11];
  const float* bv     = (const float*)d_in[12];
  const float* Wqp    = (const float*)d_in[13];
  const float* bqp    = (const float*)d_in[14];
  const float* Wkp    = (const float*)d_in[15];
  const float* bkp    = (const float*)d_in[16];
  const float* Wvp    = (const float*)d_in[17];
  const float* bvp    = (const float*)d_in[18];
  const float* Wpb    = (const float*)d_in[19];
  const float* bpb    = (const float*)d_in[20];
  const float* Wo     = (const float*)d_in[21];
  const float* bo     = (const float*)d_in[22];
  const float* w_c    = (const float*)d_in[23];
  const float* w_l    = (const float*)d_in[24];
  const float* gamma  = (const float*)d_in[25];
  float* out = (float*)d_out;

  float* p = (float*)d_ws;
  auto alloc = [&](size_t n) { float* r = p; p += n; return r; };
  float* Wcat    = alloc((size_t)DS*NPP);
  float* bcat    = alloc(NPP);
  float* WpbT    = alloc((size_t)NH*DPAIR);
  float* sn      = alloc((size_t)LQ*DS);
  float* C1      = alloc((size_t)LQ*NPP);
  float* vgb     = alloc((size_t)LQ*NH*24);
  float* Af      = alloc((size_t)NH*LQ*FE);
  float* BfT     = alloc((size_t)NH*12*LQ*4);
  float* S       = alloc((size_t)NH*LQ*LQ);
  float* pairpart= alloc((size_t)LQ*NC*NH*DPAIR);
  float* msum    = alloc((size_t)LQ*NC*NH*2);
  float* scs_g   = alloc((size_t)LQ*NH*NC);
  float* comb    = alloc((size_t)LQ*2304);
  float* scratch = alloc((size_t)2*LQ*NPP);  // psum (4*512*768) / out-GEMM partials (8*512*384)

  k_concat_w<<<dim3((DS*NPP + NPP + DPAIR*NH + 255)/256), 256, 0, stream>>>(
      Wq, Wk, Wv, Wqp, Wkp, Wvp, bq, bk, bv, bqp, bkp, bvp, Wpb, Wcat, bcat, WpbT);
  k_layernorm<<<dim3(LQ), 128, 0, stream>>>(single, ln_w, ln_b, sn);
  k_gemm_nn<<<dim3(NPP/64, LQ/64, 1), 256, 0, stream>>>(sn, Wcat, bcat, C1, nullptr, LQ, NPP, DS);
  k_rotfeat<<<dim3((LQ*NH + 255)/256), 256, 0, stream>>>(C1, rot, trans, gamma, w_c, w_l, Af, BfT, vgb);
  k_pair_chunk<<<dim3(LQ, NC), 256, 0, stream>>>(pair, WpbT, Af, (const float4*)BfT, bpb, mask, S, pairpart, msum);
  k_scs_pairout<<<dim3(LQ), 384, 0, stream>>>(msum, pairpart, scs_g, comb);
  k_attn_v<<<dim3(LQ/64, NH, 4), 256, 0, stream>>>(S, C1, vgb, scs_g, scratch);
  k_avpts<<<dim3((LQ*NH*40 + 255)/256), 256, 0, stream>>>(scratch, rot, trans, comb);
  k_gemm_nn<<<dim3(DS/64, LQ/64, 8), 256, 0, stream>>>(comb, Wo, nullptr, nullptr, scratch, LQ, DS, 2304);
  k_reduce_bias<<<dim3((LQ*DS + 255)/256), 256, 0, stream>>>(scratch, bo, out, LQ*DS, DS, 8);
}

// Round 7
// 386.632 us; speedup vs baseline: 1.0429x; 1.0429x over previous
//
#include <hip/hip_runtime.h>
#include <math.h>

// Problem constants
#define LQ    512
#define DS    384
#define DPAIR 128
#define NH    12
#define NPP   1792   // padded projection width
#define FE    48     // logits feature dim (32 q + 12 pts + 2)
#define TJC   64     // j-chunk for pair kernel
#define NC    8      // number of j-chunks (LQ/TJC)

// ---------------------------------------------------------------- concat W (+ WpbT transpose folded in)
__global__ void k_concat_w(const float* __restrict__ Wq, const float* __restrict__ Wk,
                           const float* __restrict__ Wv, const float* __restrict__ Wqp,
                           const float* __restrict__ Wkp, const float* __restrict__ Wvp,
                           const float* __restrict__ bq, const float* __restrict__ bk,
                           const float* __restrict__ bv, const float* __restrict__ bqp,
                           const float* __restrict__ bkp, const float* __restrict__ bvp,
                           const float* __restrict__ Wpb,
                           float* __restrict__ Wcat, float* __restrict__ bcat,
                           float* __restrict__ WpbT) {
  int idx = blockIdx.x * 256 + threadIdx.x;
  const int total = DS * NPP;
  if (idx < total) {
    int k = idx / NPP, c = idx % NPP;
    float v = 0.f;
    if (c < 384)       v = Wq[k*384 + c];
    else if (c < 768)  v = Wk[k*384 + c-384];
    else if (c < 1152) v = Wv[k*384 + c-768];
    else if (c < 1296) v = Wqp[k*144 + c-1152];
    else if (c < 1440) v = Wkp[k*144 + c-1296];
    else if (c < 1728) v = Wvp[k*288 + c-1440];
    Wcat[idx] = v;
  } else if (idx < total + NPP) {
    int c = idx - total;
    float v = 0.f;
    if (c < 384)       v = bq[c];
    else if (c < 768)  v = bk[c-384];
    else if (c < 1152) v = bv[c-768];
    else if (c < 1296) v = bqp[c-1152];
    else if (c < 1440) v = bkp[c-1296];
    else if (c < 1728) v = bvp[c-1440];
    bcat[c] = v;
  } else if (idx < total + NPP + DPAIR*NH) {
    int e = idx - total - NPP;
    int k = e / NH, h = e % NH;
    WpbT[h*DPAIR + k] = Wpb[e];
  }
}

// ---------------------------------------------------------------- layernorm
__global__ __launch_bounds__(128) void k_layernorm(const float* __restrict__ x,
                                                   const float* __restrict__ w,
                                                   const float* __restrict__ b,
                                                   float* __restrict__ y) {
  __shared__ float red[128];
  __shared__ float s_mu, s_rstd;
  int i = blockIdx.x, t = threadIdx.x;
  float v0 = x[i*DS + t], v1 = x[i*DS + t + 128], v2 = x[i*DS + t + 256];
  red[t] = v0 + v1 + v2; __syncthreads();
  for (int s = 64; s > 0; s >>= 1) { if (t < s) red[t] += red[t+s]; __syncthreads(); }
  if (t == 0) s_mu = red[0] * (1.f/384.f);
  __syncthreads();
  float mu = s_mu;
  float d0 = v0-mu, d1 = v1-mu, d2 = v2-mu;
  red[t] = d0*d0 + d1*d1 + d2*d2; __syncthreads();
  for (int s = 64; s > 0; s >>= 1) { if (t < s) red[t] += red[t+s]; __syncthreads(); }
  if (t == 0) s_rstd = rsqrtf(red[0] * (1.f/384.f) + 1e-5f);
  __syncthreads();
  float r = s_rstd;
  y[i*DS + t      ] = d0*r*w[t      ] + b[t      ];
  y[i*DS + t + 128] = d1*r*w[t + 128] + b[t + 128];
  y[i*DS + t + 256] = d2*r*w[t + 256] + b[t + 256];
}

// ---------------------------------------------------------------- tiled f32 GEMM (NN), optional split-K
__global__ __launch_bounds__(256) void k_gemm_nn(const float* __restrict__ A,
                                                 const float* __restrict__ B,
                                                 const float* __restrict__ bias,
                                                 float* __restrict__ C,
                                                 float* __restrict__ Cpart,
                                                 int M, int N, int K) {
  __shared__ float As[16*68];
  __shared__ float Bs[16*68];
  int t = threadIdx.x;
  int mg = t >> 4, ng = t & 15;
  int i0 = blockIdx.y * 64, j0 = blockIdx.x * 64;
  int KS = gridDim.z;
  int kper = K / KS;
  int kbeg = blockIdx.z * kper;
  float acc[4][4] = {};
  for (int k0 = kbeg; k0 < kbeg + kper; k0 += 16) {
    int e = t;
    #pragma unroll
    for (int s = 0; s < 4; s++, e += 256) {
      int m = e >> 4, k = e & 15;
      As[k*68 + m] = A[(size_t)(i0+m)*K + k0 + k];
      int k2 = e >> 6, n = e & 63;
      Bs[k2*68 + n] = B[(size_t)(k0+k2)*N + j0 + n];
    }
    __syncthreads();
    #pragma unroll
    for (int k = 0; k < 16; k++) {
      float4 av = *(const float4*)(As + k*68 + mg*4);
      float4 bv = *(const float4*)(Bs + k*68 + ng*4);
      float a[4] = {av.x, av.y, av.z, av.w};
      float b[4] = {bv.x, bv.y, bv.z, bv.w};
      #pragma unroll
      for (int y = 0; y < 4; y++)
        #pragma unroll
        for (int x = 0; x < 4; x++)
          acc[y][x] = fmaf(a[y], b[x], acc[y][x]);
    }
    __syncthreads();
  }
  if (KS == 1) {
    #pragma unroll
    for (int y = 0; y < 4; y++) {
      int m = i0 + mg*4 + y;
      #pragma unroll
      for (int x = 0; x < 4; x++) {
        int n = j0 + ng*4 + x;
        C[(size_t)m*N + n] = acc[y][x] + bias[n];
      }
    }
  } else {
    float* dst = Cpart + (size_t)blockIdx.z * M * N;
    #pragma unroll
    for (int y = 0; y < 4; y++) {
      int m = i0 + mg*4 + y;
      #pragma unroll
      for (int x = 0; x < 4; x++) {
        int n = j0 + ng*4 + x;
        dst[(size_t)m*N + n] = acc[y][x];
      }
    }
  }
}

__global__ void k_reduce_bias(const float* __restrict__ part, const float* __restrict__ bias,
                              float* __restrict__ out, int MN, int N, int KS) {
  int e = blockIdx.x * 256 + threadIdx.x;
  if (e >= MN) return;
  float s = bias[e % N];
  for (int z = 0; z < KS; z++) s += part[(size_t)z*MN + e];
  out[e] = s;
}

// ---------------------------------------------------------------- fused rotate + feature build
__global__ void k_rotfeat(const float* __restrict__ C1, const float* __restrict__ rot,
                          const float* __restrict__ trans, const float* __restrict__ gamma,
                          const float* __restrict__ w_c, const float* __restrict__ w_l,
                          float* __restrict__ Af, float* __restrict__ Bf,
                          float* __restrict__ vgb) {
  int idx = blockIdx.x * 256 + threadIdx.x;
  if (idx >= LQ*NH) return;
  int h = idx % NH, i = idx / NH;
  float R[9], tr[3];
  #pragma unroll
  for (int r = 0; r < 9; r++) R[r] = rot[(size_t)i*9 + r];
  #pragma unroll
  for (int r = 0; r < 3; r++) tr[r] = trans[(size_t)i*3 + r];

  float s  = w_c[0] * rsqrtf(32.f);
  float gp = gamma[h] * w_l[0];
  float* a  = Af + ((size_t)h*LQ + i)*FE;
  float* bb = Bf + ((size_t)h*LQ + i)*FE;
  const float* q = C1 + (size_t)i*NPP + h*32;
  const float* k = C1 + (size_t)i*NPP + 384 + h*32;
  #pragma unroll 8
  for (int d = 0; d < 32; d++) { a[d] = s*q[d]; bb[d] = k[d]; }

  const float* qp = C1 + (size_t)i*NPP + 1152 + h*12;
  const float* kp = C1 + (size_t)i*NPP + 1296 + h*12;
  float sq = 0.f, sk = 0.f;
  #pragma unroll
  for (int p = 0; p < 4; p++) {
    float x = qp[p*3], y = qp[p*3+1], z = qp[p*3+2];
    #pragma unroll
    for (int r = 0; r < 3; r++) {
      float g = fmaf(R[r*3],x, fmaf(R[r*3+1],y, fmaf(R[r*3+2],z, tr[r])));
      a[32 + p*3 + r] = gp*g;
      sq = fmaf(g,g,sq);
    }
    float xk = kp[p*3], yk = kp[p*3+1], zk = kp[p*3+2];
    #pragma unroll
    for (int r = 0; r < 3; r++) {
      float g = fmaf(R[r*3],xk, fmaf(R[r*3+1],yk, fmaf(R[r*3+2],zk, tr[r])));
      bb[32 + p*3 + r] = g;
      sk = fmaf(g,g,sk);
    }
  }
  a[44] = -0.5f*gp*sq; a[45] = 1.f; a[46] = 0.f; a[47] = 0.f;
  bb[44] = 1.f; bb[45] = -0.5f*gp*sk; bb[46] = 0.f; bb[47] = 0.f;

  const float* vp = C1 + (size_t)i*NPP + 1440 + h*24;
  float* vd = vgb + ((size_t)i*NH + h)*24;
  #pragma unroll
  for (int p = 0; p < 8; p++) {
    float x = vp[p*3], y = vp[p*3+1], z = vp[p*3+2];
    #pragma unroll
    for (int r = 0; r < 3; r++)
      vd[p*3 + r] = fmaf(R[r*3],x, fmaf(R[r*3+1],y, fmaf(R[r*3+2],z, tr[r])));
  }
}

// ---------------------------------------------------------------- batched NT GEMM: S[h] = A_h @ B_h^T  (K=48)
__global__ __launch_bounds__(256) void k_logits_nt(const float* __restrict__ Af,
                                                   const float* __restrict__ Bf,
                                                   float* __restrict__ S) {
  __shared__ float As[48*68];
  __shared__ float Bs[48*68];
  int h = blockIdx.z;
  int i0 = blockIdx.y * 64, j0 = blockIdx.x * 64;
  int t = threadIdx.x;
  int mg = t >> 4, ng = t & 15;
  const float* Ah = Af + (size_t)h*LQ*FE;
  const float* Bh = Bf + (size_t)h*LQ*FE;
  for (int e = t; e < 64*48; e += 256) {
    int m = e / 48, k = e % 48;
    As[k*68 + m] = Ah[(size_t)(i0+m)*FE + k];
    Bs[k*68 + m] = Bh[(size_t)(j0+m)*FE + k];
  }
  __syncthreads();
  float acc[4][4] = {};
  #pragma unroll 8
  for (int k = 0; k < 48; k++) {
    float4 av = *(const float4*)(As + k*68 + mg*4);
    float4 bv = *(const float4*)(Bs + k*68 + ng*4);
    float a[4] = {av.x, av.y, av.z, av.w};
    float b[4] = {bv.x, bv.y, bv.z, bv.w};
    #pragma unroll
    for (int y = 0; y < 4; y++)
      #pragma unroll
      for (int x = 0; x < 4; x++)
        acc[y][x] = fmaf(a[y], b[x], acc[y][x]);
  }
  #pragma unroll
  for (int y = 0; y < 4; y++) {
    #pragma unroll
    for (int x = 0; x < 4; x++)
      S[((size_t)h*LQ + i0 + mg*4 + y)*LQ + j0 + ng*4 + x] = acc[y][x];
  }
}

// ---------------------------------------------------------------- pair chunk: bias + chunk softmax + partial pair_out
// grid (i=512, c=8), 256 threads. One 64x128 f32 pair tile per block, loaded once.
__global__ __launch_bounds__(256, 2) void k_pair_chunk(
    const float* __restrict__ pair, const float* __restrict__ WpbT,
    const float* __restrict__ bpb, const float* __restrict__ mask,
    float* __restrict__ S, float* __restrict__ pairpart, float* __restrict__ msum) {
  __shared__ float tile[TJC*133];   // 34 KB, padded stride
  __shared__ float wt[NH*TJC];      // 3 KB
  int i = blockIdx.x, c = blockIdx.y, t = threadIdx.x;
  int j0 = c*TJC;

  // stage 64x128 tile, fully coalesced
  const float4* src = (const float4*)(pair + ((size_t)i*LQ + j0)*DPAIR);
  #pragma unroll
  for (int u = 0; u < 8; u++) {
    int e = t + u*256; int row = e >> 5, c4 = e & 31;
    *(float4*)&tile[row*133 + c4*4] = src[e];
  }

  // load logits for this chunk (3 heads per wave)
  int j = t & 63;
  int hg = __builtin_amdgcn_readfirstlane(t >> 6);   // 0..3, wave-uniform
  int h0 = hg*3;
  float l[3];
  #pragma unroll
  for (int q = 0; q < 3; q++)
    l[q] = S[((size_t)(h0+q)*LQ + i)*LQ + j0 + j] + bpb[h0+q];
  bool dead = (mask[i] * mask[j0 + j] <= 0.f);
  __syncthreads();

  // phase A: pair-bias GEMV from LDS tile, weights wave-uniform
  {
    const float* w0p = WpbT + (size_t)(h0+0)*DPAIR;
    const float* w1p = WpbT + (size_t)(h0+1)*DPAIR;
    const float* w2p = WpbT + (size_t)(h0+2)*DPAIR;
    float a0 = 0.f, a1 = 0.f, a2 = 0.f;
    #pragma unroll 8
    for (int k = 0; k < DPAIR; k += 4) {
      float4 pv = *(const float4*)&tile[j*133 + k];
      float4 w0 = *(const float4*)(w0p + k);
      float4 w1 = *(const float4*)(w1p + k);
      float4 w2 = *(const float4*)(w2p + k);
      a0 = fmaf(pv.x,w0.x, fmaf(pv.y,w0.y, fmaf(pv.z,w0.z, fmaf(pv.w,w0.w, a0))));
      a1 = fmaf(pv.x,w1.x, fmaf(pv.y,w1.y, fmaf(pv.z,w1.z, fmaf(pv.w,w1.w, a1))));
      a2 = fmaf(pv.x,w2.x, fmaf(pv.y,w2.y, fmaf(pv.z,w2.z, fmaf(pv.w,w2.w, a2))));
    }
    l[0] += a0; l[1] += a1; l[2] += a2;
    if (dead) { l[0] = -1e9f; l[1] = -1e9f; l[2] = -1e9f; }
  }

  // chunk softmax: per-wave shuffle reduce, 3 heads
  #pragma unroll
  for (int q = 0; q < 3; q++) {
    float m = l[q];
    #pragma unroll
    for (int o = 32; o > 0; o >>= 1) m = fmaxf(m, __shfl_xor(m, o, 64));
    float w = __expf(l[q] - m);
    float sm = w;
    #pragma unroll
    for (int o = 32; o > 0; o >>= 1) sm += __shfl_xor(sm, o, 64);
    wt[(h0+q)*TJC + j] = w;
    S[((size_t)(h0+q)*LQ + i)*LQ + j0 + j] = w;
    if (j == 0) {
      float* dst = msum + (((size_t)i*NC + c)*NH + h0 + q)*2;
      dst[0] = m; dst[1] = sm;
    }
  }
  __syncthreads();

  // phase C: partial pair_out from the same tile
  int dg = t & 31, strip = t >> 5, jb = strip*8;
  float4 pv[8];
  #pragma unroll
  for (int q = 0; q < 8; q++) pv[q] = *(const float4*)&tile[(jb+q)*133 + dg*4];
  float4 acc[NH];
  #pragma unroll
  for (int h = 0; h < NH; h++) acc[h] = make_float4(0.f,0.f,0.f,0.f);
  #pragma unroll
  for (int h = 0; h < NH; h++) {
    float4 w0 = *(const float4*)&wt[h*TJC + jb];
    float4 w1 = *(const float4*)&wt[h*TJC + jb + 4];
    float wq[8] = {w0.x,w0.y,w0.z,w0.w,w1.x,w1.y,w1.z,w1.w};
    float4 a = acc[h];
    #pragma unroll
    for (int q = 0; q < 8; q++) {
      a.x = fmaf(wq[q], pv[q].x, a.x);
      a.y = fmaf(wq[q], pv[q].y, a.y);
      a.z = fmaf(wq[q], pv[q].z, a.z);
      a.w = fmaf(wq[q], pv[q].w, a.w);
    }
    acc[h] = a;
  }
  __syncthreads();   // all tile reads done; reuse tile as reduction scratch

  // reduce 8 strips (two halves of 4) -> pairpart
  float4* red4 = (float4*)tile;    // 4*12*32 = 1536 float4 <= 2128 cap
  float4 tot[2];
  tot[0] = make_float4(0.f,0.f,0.f,0.f);
  tot[1] = make_float4(0.f,0.f,0.f,0.f);
  #pragma unroll
  for (int half = 0; half < 2; half++) {
    if ((strip >> 2) == half) {
      #pragma unroll
      for (int h = 0; h < NH; h++)
        red4[(((strip & 3)*NH) + h)*32 + dg] = acc[h];
    }
    __syncthreads();
    for (int e = t, u = 0; e < NH*32; e += 256, u++) {
      int rh = e >> 5, rd = e & 31;
      #pragma unroll
      for (int s4 = 0; s4 < 4; s4++) {
        float4 v = red4[((s4*NH) + rh)*32 + rd];
        tot[u].x += v.x; tot[u].y += v.y; tot[u].z += v.z; tot[u].w += v.w;
      }
    }
    __syncthreads();
  }
  for (int e = t, u = 0; e < NH*32; e += 256, u++) {
    int rh = e >> 5, rd = e & 31;
    *(float4*)&pairpart[(((size_t)i*NC + c)*NH + rh)*DPAIR + rd*4] = tot[u];
  }
}

// ---------------------------------------------------------------- per-chunk softmax scales + pair_out combine
__global__ __launch_bounds__(384) void k_scs_pairout(
    const float* __restrict__ msum, const float* __restrict__ pairpart,
    float* __restrict__ scs_g, float* __restrict__ comb) {
  __shared__ float scs[NH*NC];
  int i = blockIdx.x, t = threadIdx.x;
  if (t < NH) {
    float m = -3.0e38f;
    float mc[NC], sc_[NC];
    #pragma unroll
    for (int c = 0; c < NC; c++) {
      const float* p = msum + (((size_t)i*NC + c)*NH + t)*2;
      mc[c] = p[0]; sc_[c] = p[1];
      m = fmaxf(m, mc[c]);
    }
    float s = 0.f;
    #pragma unroll
    for (int c = 0; c < NC; c++) s += sc_[c] * __expf(mc[c] - m);
    float inv = 1.f / s;
    #pragma unroll
    for (int c = 0; c < NC; c++) {
      float v = __expf(mc[c] - m) * inv;
      scs[t*NC + c] = v;
      scs_g[((size_t)i*NH + t)*NC + c] = v;
    }
  }
  __syncthreads();
  int h = t >> 5, d = t & 31;
  float4 tot = make_float4(0.f,0.f,0.f,0.f);
  #pragma unroll
  for (int c = 0; c < NC; c++) {
    float sc = scs[h*NC + c];
    float4 v = *(const float4*)&pairpart[(((size_t)i*NC + c)*NH + h)*DPAIR + d*4];
    tot.x = fmaf(v.x, sc, tot.x); tot.y = fmaf(v.y, sc, tot.y);
    tot.z = fmaf(v.z, sc, tot.z); tot.w = fmaf(v.w, sc, tot.w);
  }
  *(float4*)&comb[(size_t)i*2304 + 768 + h*DPAIR + d*4] = tot;
}

// ---------------------------------------------------------------- attn @ [v | vg] per head, split-K=4 -> psum
__global__ __launch_bounds__(256) void k_attn_v(const float* __restrict__ attn,
                                                const float* __restrict__ C1,
                                                const float* __restrict__ vg,
                                                const float* __restrict__ scs,
                                                float* __restrict__ psum) {
  __shared__ float As[64*68];   // [j][m] (transposed)
  __shared__ float Vs[64*68];   // [j][n], n<56 valid
  int i0 = blockIdx.x * 64;
  int h = blockIdx.y;
  int z = blockIdx.z;
  int t = threadIdx.x;
  int mg = t >> 4, ng = t & 15;
  float acc[4][4] = {};
  for (int k0 = z*128; k0 < z*128 + 128; k0 += 64) {
    int c = k0 >> 6;
    __syncthreads();
    for (int e = t; e < 64*64; e += 256) {
      int m = e >> 6, j = e & 63;
      float sc = scs[((size_t)(i0+m)*NH + h)*NC + c];
      As[j*68 + m] = attn[((size_t)h*LQ + i0 + m)*LQ + k0 + j] * sc;
    }
    for (int e = t; e < 64*64; e += 256) {
      int j = e >> 6, cc = e & 63;
      float v = 0.f;
      if (cc < 32)      v = C1[(size_t)(k0+j)*NPP + 768 + h*32 + cc];
      else if (cc < 56) v = vg[((size_t)(k0+j)*NH + h)*24 + (cc-32)];
      Vs[j*68 + cc] = v;
    }
    __syncthreads();
    #pragma unroll 4
    for (int j = 0; j < 64; j++) {
      float4 av = *(const float4*)(As + j*68 + mg*4);
      float4 bv = *(const float4*)(Vs + j*68 + ng*4);
      float a[4] = {av.x, av.y, av.z, av.w};
      float b[4] = {bv.x, bv.y, bv.z, bv.w};
      #pragma unroll
      for (int y = 0; y < 4; y++)
        #pragma unroll
        for (int x = 0; x < 4; x++)
          acc[y][x] = fmaf(a[y], b[x], acc[y][x]);
    }
  }
  #pragma unroll
  for (int y = 0; y < 4; y++) {
    int i = i0 + mg*4 + y;
    #pragma unroll
    for (int x = 0; x < 4; x++) {
      int n = ng*4 + x;
      psum[(((size_t)z*LQ + i)*NH + h)*64 + n] = acc[y][x];
    }
  }
}

// ---------------------------------------------------------------- fused av_reduce + pts_feat
__global__ void k_avpts(const float* __restrict__ psum, const float* __restrict__ rot,
                        const float* __restrict__ trans, float* __restrict__ comb) {
  int idx = blockIdx.x * 256 + threadIdx.x;
  if (idx >= LQ*NH*40) return;
  int w = idx % 40; int ih = idx / 40; int h = ih % NH; int i = ih / NH;
  size_t base = ((size_t)i*NH + h)*64;
  if (w < 32) {
    float s = 0.f;
    for (int z = 0; z < 4; z++) s += psum[(size_t)z*LQ*NH*64 + base + w];
    comb[(size_t)i*2304 + h*32 + w] = s;
  } else {
    int p = w - 32;
    float g[3];
    #pragma unroll
    for (int r = 0; r < 3; r++) {
      int n = 32 + p*3 + r;
      float s = 0.f;
      for (int z = 0; z < 4; z++) s += psum[(size_t)z*LQ*NH*64 + base + n];
      g[r] = s;
    }
    const float* R = rot + (size_t)i*9;
    const float* tr = trans + (size_t)i*3;
    float x = g[0]-tr[0], y = g[1]-tr[1], z = g[2]-tr[2];
    float lx = fmaf(R[0],x, fmaf(R[3],y, R[6]*z));
    float ly = fmaf(R[1],x, fmaf(R[4],y, R[7]*z));
    float lz = fmaf(R[2],x, fmaf(R[5],y, R[8]*z));
    float nrm = sqrtf(fmaf(lx,lx, fmaf(ly,ly, lz*lz)));
    float* dst = comb + (size_t)i*2304 + 384 + (h*8 + p)*4;
    dst[0] = nrm; dst[1] = lx; dst[2] = ly; dst[3] = lz;
  }
}

// ================================================================ launcher
extern "C" void kernel_launch(void* const* d_in, const int* in_sizes, int n_in,
                              void* d_out, int out_size, void* d_ws, size_t ws_size,
                              hipStream_t stream) {
  const float* single = (const float*)d_in[0];
  const float* pair   = (const float*)d_in[1];
  const float* rot    = (const float*)d_in[2];
  const float* trans  = (const float*)d_in[3];
  const float* mask   = (const float*)d_in[4];
  const float* ln_w   = (const float*)d_in[5];
  const float* ln_b   = (const float*)d_in[6];
  const float* Wq     = (const float*)d_in[7];
  const float* bq     = (const float*)d_in[8];
  const float* Wk     = (const float*)d_in[9];
  const float* bk     = (const float*)d_in[10];
  const float* Wv     = (const float*)d_in[11];
  const float* bv     = (const float*)d_in[12];
  const float* Wqp    = (const float*)d_in[13];
  const float* bqp    = (const float*)d_in[14];
  const float* Wkp    = (const float*)d_in[15];
  const float* bkp    = (const float*)d_in[16];
  const float* Wvp    = (const float*)d_in[17];
  const float* bvp    = (const float*)d_in[18];
  const float* Wpb    = (const float*)d_in[19];
  const float* bpb    = (const float*)d_in[20];
  const float* Wo     = (const float*)d_in[21];
  const float* bo     = (const float*)d_in[22];
  const float* w_c    = (const float*)d_in[23];
  const float* w_l    = (const float*)d_in[24];
  const float* gamma  = (const float*)d_in[25];
  float* out = (float*)d_out;

  float* p = (float*)d_ws;
  auto alloc = [&](size_t n) { float* r = p; p += n; return r; };
  float* Wcat    = alloc((size_t)DS*NPP);
  float* bcat    = alloc(NPP);
  float* WpbT    = alloc((size_t)NH*DPAIR);
  float* sn      = alloc((size_t)LQ*DS);
  float* C1      = alloc((size_t)LQ*NPP);
  float* vgb     = alloc((size_t)LQ*NH*24);
  float* Af      = alloc((size_t)NH*LQ*FE);
  float* Bf      = alloc((size_t)NH*LQ*FE);
  float* S       = alloc((size_t)NH*LQ*LQ);
  float* pairpart= alloc((size_t)LQ*NC*NH*DPAIR);
  float* msum    = alloc((size_t)LQ*NC*NH*2);
  float* scs_g   = alloc((size_t)LQ*NH*NC);
  float* comb    = alloc((size_t)LQ*2304);
  float* scratch = alloc((size_t)2*LQ*NPP);  // psum (4*512*768) / out-GEMM partials (8*512*384)

  k_concat_w<<<dim3((DS*NPP + NPP + DPAIR*NH + 255)/256), 256, 0, stream>>>(
      Wq, Wk, Wv, Wqp, Wkp, Wvp, bq, bk, bv, bqp, bkp, bvp, Wpb, Wcat, bcat, WpbT);
  k_layernorm<<<dim3(LQ), 128, 0, stream>>>(single, ln_w, ln_b, sn);
  k_gemm_nn<<<dim3(NPP/64, LQ/64, 1), 256, 0, stream>>>(sn, Wcat, bcat, C1, nullptr, LQ, NPP, DS);
  k_rotfeat<<<dim3((LQ*NH + 255)/256), 256, 0, stream>>>(C1, rot, trans, gamma, w_c, w_l, Af, Bf, vgb);
  k_logits_nt<<<dim3(LQ/64, LQ/64, NH), 256, 0, stream>>>(Af, Bf, S);
  k_pair_chunk<<<dim3(LQ, NC), 256, 0, stream>>>(pair, WpbT, bpb, mask, S, pairpart, msum);
  k_scs_pairout<<<dim3(LQ), 384, 0, stream>>>(msum, pairpart, scs_g, comb);
  k_attn_v<<<dim3(LQ/64, NH, 4), 256, 0, stream>>>(S, C1, vgb, scs_g, scratch);
  k_avpts<<<dim3((LQ*NH*40 + 255)/256), 256, 0, stream>>>(scratch, rot, trans, comb);
  k_gemm_nn<<<dim3(DS/64, LQ/64, 8), 256, 0, stream>>>(comb, Wo, nullptr, nullptr, scratch, LQ, DS, 2304);
  k_reduce_bias<<<dim3((LQ*DS + 255)/256), 256, 0, stream>>>(scratch, bo, out, LQ*DS, DS, 8);
}